// Round 6
// baseline (504.438 us; speedup 1.0000x reference)
//
#include <hip/hip_runtime.h>
#include <math.h>

#define BB 2
#define SS 2048
#define DD 2048
#define QH 16
#define NKV 4
#define HD 128
#define REP 4           // QH / NKV
#define NEG_INF_F (-1e9f)

typedef __bf16 bfrag __attribute__((ext_vector_type(8)));   // 4 VGPRs
typedef float  ffrag __attribute__((ext_vector_type(4)));   // 4 VGPRs

__device__ inline unsigned short f2bf(float f) {
    unsigned u = __builtin_bit_cast(unsigned, f);
    u += 0x7fff + ((u >> 16) & 1);          // round-to-nearest-even
    return (unsigned short)(u >> 16);
}
__device__ inline float bf2f(unsigned short u) {
    unsigned v = (unsigned)u << 16;
    return __builtin_bit_cast(float, v);
}
__device__ inline bfrag ld_frag(const unsigned short* p) {
    uint4 u = *(const uint4*)p;
    return __builtin_bit_cast(bfrag, u);
}
__device__ inline void async16(const void* g, void* l) {
    __builtin_amdgcn_global_load_lds(
        (const __attribute__((address_space(1))) unsigned int*)g,
        (__attribute__((address_space(3))) unsigned int*)l, 16, 0, 0);
}

// ---------------------------------------------------------------------------
// Kernel A: elementwise cast x fp32 -> bf16 (8 elems/thread).
// ---------------------------------------------------------------------------
__global__ void cast_x_kernel(const float* __restrict__ x,
                              unsigned short* __restrict__ xb, int n)
{
    const int i = (blockIdx.x * blockDim.x + threadIdx.x) * 8;
    if (i >= n) return;
    float4 a = *(const float4*)(x + i);
    float4 b = *(const float4*)(x + i + 4);
    unsigned short o[8];
    o[0] = f2bf(a.x); o[1] = f2bf(a.y); o[2] = f2bf(a.z); o[3] = f2bf(a.w);
    o[4] = f2bf(b.x); o[5] = f2bf(b.y); o[6] = f2bf(b.z); o[7] = f2bf(b.w);
    *(uint4*)(xb + i) = *(uint4*)o;
}

// ---------------------------------------------------------------------------
// Kernel B: tiled transpose-cast. in: [batch][R][C] fp32 -> out: [batch][C][R]
// bf16. 32x32 tiles via padded LDS; both sides coalesced.
// ---------------------------------------------------------------------------
__global__ __launch_bounds__(256) void tcast_kernel(
    const float* __restrict__ in, unsigned short* __restrict__ out,
    int R, int C)
{
    __shared__ float tile[32][33];
    const size_t bofs = (size_t)blockIdx.z * R * C;
    in  += bofs;
    out += bofs;
    const int c0 = blockIdx.x * 32, r0 = blockIdx.y * 32;
    const int tx = threadIdx.x & 31, ty = threadIdx.x >> 5;   // ty: 0..7
    #pragma unroll
    for (int k = 0; k < 4; ++k)
        tile[ty + 8 * k][tx] = in[(size_t)(r0 + ty + 8 * k) * C + c0 + tx];
    __syncthreads();
    #pragma unroll
    for (int k = 0; k < 4; ++k)
        out[(size_t)(c0 + ty + 8 * k) * R + r0 + tx] =
            f2bf(tile[tx][ty + 8 * k]);
}

// ---------------------------------------------------------------------------
// Kernel C: bf16 MFMA GEMM, m97 structure. 128x128 tile, BK=32, 4 waves x
// 4x4 16x16x32 MFMA, global_load_lds width-16 staging.
// mode 0: fp32 out [row][2048] (oproj).
// mode 1: qkv — q,k natural bf16; v stored TRANSPOSED to vt[b][n][h][s].
// ---------------------------------------------------------------------------
__global__ __launch_bounds__(256) void gemm_bt_kernel(
    const unsigned short* __restrict__ A,
    const unsigned short* __restrict__ Bt,
    unsigned short* __restrict__ q_out, unsigned short* __restrict__ k_out,
    unsigned short* __restrict__ vt_out, float* __restrict__ f_out,
    int mode)
{
    const int m0 = blockIdx.x * 128;
    const int n0 = blockIdx.y * 128;
    const int tid  = threadIdx.x;
    const int w    = tid >> 6, lane = tid & 63;
    const int l16  = lane & 15, quad = lane >> 4;
    const int wm = (w >> 1) * 64, wn = (w & 1) * 64;

    __shared__ unsigned short As[128 * 32];   // [m][k], 64 B rows
    __shared__ unsigned short Bs[128 * 32];   // [n][k]

    ffrag acc[4][4];
    #pragma unroll
    for (int mi = 0; mi < 4; ++mi)
        #pragma unroll
        for (int ni = 0; ni < 4; ++ni)
            acc[mi][ni] = (ffrag){0.f, 0.f, 0.f, 0.f};

    for (int k0 = 0; k0 < 2048; k0 += 32) {
        __syncthreads();
        #pragma unroll
        for (int j = 0; j < 2; ++j) {
            const int i   = (j * 4 + w) * 64 + lane;   // chunk 0..511
            const int row = i >> 2, seg = i & 3;
            async16(&A [(size_t)(m0 + row) * 2048 + k0 + seg * 8],
                    (char*)As + i * 16);
            async16(&Bt[(size_t)(n0 + row) * 2048 + k0 + seg * 8],
                    (char*)Bs + i * 16);
        }
        __syncthreads();

        bfrag af[4], bfr[4];
        #pragma unroll
        for (int mi = 0; mi < 4; ++mi)
            af[mi] = ld_frag(&As[(wm + mi * 16 + l16) * 32 + quad * 8]);
        #pragma unroll
        for (int ni = 0; ni < 4; ++ni)
            bfr[ni] = ld_frag(&Bs[(wn + ni * 16 + l16) * 32 + quad * 8]);
        #pragma unroll
        for (int mi = 0; mi < 4; ++mi)
            #pragma unroll
            for (int ni = 0; ni < 4; ++ni)
                acc[mi][ni] = __builtin_amdgcn_mfma_f32_16x16x32_bf16(
                    af[mi], bfr[ni], acc[mi][ni], 0, 0, 0);
    }

    if (mode == 0) {
        #pragma unroll
        for (int mi = 0; mi < 4; ++mi)
            #pragma unroll
            for (int ni = 0; ni < 4; ++ni) {
                const int col = n0 + wn + ni * 16 + l16;
                #pragma unroll
                for (int r = 0; r < 4; ++r) {
                    const int row = m0 + wm + mi * 16 + quad * 4 + r;
                    f_out[(size_t)row * 2048 + col] = acc[mi][ni][r];
                }
            }
    } else if (n0 < 2560) {
        unsigned short* dst;
        int colbase, stride;
        if (n0 < 2048)      { dst = q_out; colbase = n0;        stride = 2048; }
        else                { dst = k_out; colbase = n0 - 2048; stride = 512;  }
        #pragma unroll
        for (int mi = 0; mi < 4; ++mi)
            #pragma unroll
            for (int ni = 0; ni < 4; ++ni) {
                const int col = colbase + wn + ni * 16 + l16;
                #pragma unroll
                for (int r = 0; r < 4; ++r) {
                    const int row = m0 + wm + mi * 16 + quad * 4 + r;
                    dst[(size_t)row * stride + col] = f2bf(acc[mi][ni][r]);
                }
            }
    } else {
        // v region: transposed store vt[b][n][h][s], 4 bf16 (s..s+3) packed
        const int c3 = n0 - 2560;
        #pragma unroll
        for (int mi = 0; mi < 4; ++mi)
            #pragma unroll
            for (int ni = 0; ni < 4; ++ni) {
                const int col = c3 + wn + ni * 16 + l16;   // 0..511
                const int nh = col >> 7, h = col & 127;
                const int row0 = m0 + wm + mi * 16 + quad * 4;
                const int b = row0 >> 11, s = row0 & 2047;
                unsigned short pk[4];
                #pragma unroll
                for (int r = 0; r < 4; ++r) pk[r] = f2bf(acc[mi][ni][r]);
                *(uint2*)&vt_out[(((size_t)b * NKV + nh) * HD + h) * SS + s] =
                    *(uint2*)pk;
            }
    }
}

// ---------------------------------------------------------------------------
// Kernel D: RoPE in-place on bf16 q and k.
// ---------------------------------------------------------------------------
__global__ void rope_kernel(unsigned short* __restrict__ q,
                            unsigned short* __restrict__ k,
                            const int* __restrict__ positions)
{
    const int qpairs = BB * SS * QH * 64;
    const int kpairs = BB * SS * NKV * 64;
    int idx = blockIdx.x * blockDim.x + threadIdx.x;
    unsigned short* base;
    int nh;
    if (idx < qpairs) { base = q; nh = QH; }
    else {
        idx -= qpairs;
        if (idx >= kpairs) return;
        base = k; nh = NKV;
    }
    const int hh   = idx & 63;
    const int rest = idx >> 6;
    const int head = rest % nh;
    const int bs   = rest / nh;
    const int s    = bs % SS;

    unsigned short* p = base + ((size_t)bs * nh + head) * HD;
    const float pos = (float)positions[s];
    const float inv_ts = powf(10000.0f, -(float)hh * (1.0f / 64.0f));
    const float angle = pos * inv_ts;
    const float sn = sinf(angle), cs = cosf(angle);
    const float x1 = bf2f(p[hh]), x2 = bf2f(p[hh + 64]);
    p[hh]      = f2bf(x1 * cs - x2 * sn);
    p[hh + 64] = f2bf(x2 * cs + x1 * sn);
}

// ---------------------------------------------------------------------------
// Kernel E: causal flash attention v3 — single Q-tile per block (no spills),
// LPT scheduling (heaviest tile first), 1024 blocks.
//  - K LDS [hchunk][t][32], V^T LDS [tchunk][h][32]: async16 staging,
//    lane-sequential LDS writes = conflict-free.
//  - P per-wave [kchunk][16][34] (pad-17-word rows, ~2-way max).
// ---------------------------------------------------------------------------
__global__ __launch_bounds__(256, 3) void attn_kernel(
    const unsigned short* __restrict__ qb,
    const unsigned short* __restrict__ kb,
    const unsigned short* __restrict__ vt,
    unsigned short* __restrict__ o)
{
    const int tile = 31 - blockIdx.x;          // LPT: heavy blocks first
    const int s0 = tile * 64;
    const int bh = blockIdx.y;
    const int b  = bh / QH, qh = bh % QH;
    const int n  = qh / REP;

    const int tid  = threadIdx.x;
    const int w    = tid >> 6;
    const int lane = tid & 63;
    const int l16  = lane & 15;
    const int quad = lane >> 4;

    __shared__ unsigned short Ks[4][64][32];    // 16 KB
    __shared__ unsigned short Vs[2][128][32];   // 16 KB
    __shared__ unsigned short Ps[4][2][16][34]; // 8.7 KB

    bfrag qf[4];
    {
        const unsigned short* qp =
            qb + ((size_t)(b * SS + s0 + w * 16 + l16) * QH + qh) * HD + quad * 8;
        #pragma unroll
        for (int c = 0; c < 4; ++c)
            qf[c] = ld_frag(qp + c * 32);
    }
    ffrag oacc[8];
    #pragma unroll
    for (int t = 0; t < 8; ++t) oacc[t] = (ffrag){0.f, 0.f, 0.f, 0.f};
    float mr[4], lr[4];
    #pragma unroll
    for (int r = 0; r < 4; ++r) { mr[r] = -1e30f; lr[r] = 0.0f; }
    const float scale = 0.08838834764831845f;   // 1/sqrt(128)
    const int rbase = s0 + w * 16 + quad * 4;

    const unsigned short* kbase = kb + (size_t)b * (SS * NKV * HD) + n * HD;
    const unsigned short* vbase = vt + ((size_t)b * NKV + n) * HD * SS;

    for (int t0 = 0; t0 <= s0; t0 += 64) {
        __syncthreads();   // previous iteration's fragment reads complete
        #pragma unroll
        for (int j = 0; j < 4; ++j) {
            const int s = j * 256 + tid;
            {   // K tile: [c=h-chunk][t][seg]
                const int c = s >> 8, t = (s >> 2) & 63, seg = s & 3;
                async16(kbase + (size_t)(t0 + t) * (NKV * HD) + c * 32 + seg * 8,
                        (char*)Ks + s * 16);
            }
            {   // V^T tile: [c=t-chunk][h][seg]
                const int c = s >> 9, h = (s >> 2) & 127, seg = s & 3;
                async16(vbase + (size_t)h * SS + t0 + c * 32 + seg * 8,
                        (char*)Vs + s * 16);
            }
        }
        __syncthreads();   // staging drained

        // --- QK^T
        ffrag sc[4];
        #pragma unroll
        for (int t = 0; t < 4; ++t) sc[t] = (ffrag){0.f, 0.f, 0.f, 0.f};
        #pragma unroll
        for (int c = 0; c < 4; ++c) {
            #pragma unroll
            for (int t = 0; t < 4; ++t) {
                bfrag kfr = ld_frag(&Ks[c][t * 16 + l16][quad * 8]);
                sc[t] = __builtin_amdgcn_mfma_f32_16x16x32_bf16(
                    qf[c], kfr, sc[t], 0, 0, 0);
            }
        }

        // --- mask + online softmax (C layout: row=quad*4+r, col=l16)
        const bool diag = (t0 == s0);
        float sv[4][4];
        #pragma unroll
        for (int t = 0; t < 4; ++t) {
            const int col = t0 + t * 16 + l16;
            #pragma unroll
            for (int r = 0; r < 4; ++r) {
                float s = sc[t][r] * scale;
                if (diag && (col > rbase + r)) s = NEG_INF_F;
                sv[t][r] = s;
            }
        }
        #pragma unroll
        for (int r = 0; r < 4; ++r) {
            float tm = fmaxf(fmaxf(sv[0][r], sv[1][r]),
                             fmaxf(sv[2][r], sv[3][r]));
            #pragma unroll
            for (int off = 1; off < 16; off <<= 1)
                tm = fmaxf(tm, __shfl_xor(tm, off));
            const float mnew  = fmaxf(mr[r], tm);
            const float alpha = __expf(mr[r] - mnew);
            float p0 = __expf(sv[0][r] - mnew);
            float p1 = __expf(sv[1][r] - mnew);
            float p2 = __expf(sv[2][r] - mnew);
            float p3 = __expf(sv[3][r] - mnew);
            float ps = p0 + p1 + p2 + p3;
            #pragma unroll
            for (int off = 1; off < 16; off <<= 1)
                ps += __shfl_xor(ps, off);
            lr[r] = lr[r] * alpha + ps;
            mr[r] = mnew;
            #pragma unroll
            for (int t = 0; t < 8; ++t) oacc[t][r] *= alpha;
            const int row = quad * 4 + r;
            Ps[w][0][row][0 * 16 + l16] = f2bf(p0);
            Ps[w][0][row][1 * 16 + l16] = f2bf(p1);
            Ps[w][1][row][0 * 16 + l16] = f2bf(p2);
            Ps[w][1][row][1 * 16 + l16] = f2bf(p3);
        }
        // wave-private Ps: same-wave LDS ordering, no barrier needed

        // --- PV
        #pragma unroll
        for (int c = 0; c < 2; ++c) {
            bfrag pf = ld_frag(&Ps[w][c][l16][quad * 8]);
            #pragma unroll
            for (int t = 0; t < 8; ++t) {
                bfrag vf = ld_frag(&Vs[c][t * 16 + l16][quad * 8]);
                oacc[t] = __builtin_amdgcn_mfma_f32_16x16x32_bf16(
                    pf, vf, oacc[t], 0, 0, 0);
            }
        }
    }

    #pragma unroll
    for (int r = 0; r < 4; ++r) {
        const float invl = 1.0f / lr[r];
        const int row = rbase + r;
        unsigned short* op = o + ((size_t)(b * SS + row) * QH + qh) * HD;
        #pragma unroll
        for (int t = 0; t < 8; ++t)
            op[t * 16 + l16] = f2bf(oacc[t][r] * invl);
    }
}

// ---------------------------------------------------------------------------
extern "C" void kernel_launch(void* const* d_in, const int* in_sizes, int n_in,
                              void* d_out, int out_size, void* d_ws,
                              size_t ws_size, hipStream_t stream)
{
    const float* x         = (const float*)d_in[0];
    const int*   positions = (const int*)d_in[1];
    const float* Wq        = (const float*)d_in[2];
    const float* Wk        = (const float*)d_in[3];
    const float* Wv        = (const float*)d_in[4];
    const float* Wo        = (const float*)d_in[5];
    float* out = (float*)d_out;

    // workspace (60 MB):
    //   [ 0,16)  xb  bf16 [4096][2048]      -- aliased by opre after qkv gemm
    //   [16,28)  Wqkvt bf16 [3072][2048]    (B^T)
    //   [28,36)  Wot bf16 [2048][2048]      (B^T)
    //   [36,52)  qbf bf16 [4096][16][128]
    //   [52,56)  kbf bf16 [4096][4][128]
    //   [56,60)  vtb bf16 [2][4][128][2048] (V^T: [b][n][h][s])
    char* ws = (char*)d_ws;
    unsigned short* xb    = (unsigned short*)ws;
    unsigned short* Wqkvt = (unsigned short*)(ws + (16u << 20));
    unsigned short* Wot   = (unsigned short*)(ws + (28u << 20));
    unsigned short* qbf   = (unsigned short*)(ws + (36u << 20));
    unsigned short* kbf   = (unsigned short*)(ws + (52u << 20));
    unsigned short* vtb   = (unsigned short*)(ws + (56u << 20));
    unsigned short* opre  = xb;   // alias: xb dead after qkv gemm

    const int nx = BB * SS * DD;                     // 8,388,608
    cast_x_kernel<<<nx / (8 * 256), 256, 0, stream>>>(x, xb, nx);

    // weights -> B^T bf16
    tcast_kernel<<<dim3(4, 64, 16), 256, 0, stream>>>(Wq, Wqkvt, 2048, 128);
    tcast_kernel<<<dim3(4, 64, 4), 256, 0, stream>>>(
        Wk, Wqkvt + (size_t)16 * 128 * 2048, 2048, 128);
    tcast_kernel<<<dim3(4, 64, 4), 256, 0, stream>>>(
        Wv, Wqkvt + (size_t)20 * 128 * 2048, 2048, 128);
    tcast_kernel<<<dim3(64, 64, 1), 256, 0, stream>>>(Wo, Wot, 2048, 2048);

    // qkv projection (v stored transposed)
    gemm_bt_kernel<<<dim3(32, 24), 256, 0, stream>>>(
        xb, Wqkvt, qbf, kbf, vtb, nullptr, 1);

    const int pairs = BB * SS * (QH + NKV) * 64;
    rope_kernel<<<(pairs + 255) / 256, 256, 0, stream>>>(qbf, kbf, positions);

    // attention: 1024 blocks, single tile each, heavy-first
    dim3 g2(32, BB * QH);
    attn_kernel<<<g2, 256, 0, stream>>>(qbf, kbf, vtb, opre);

    // output projection
    gemm_bt_kernel<<<dim3(32, 16), 256, 0, stream>>>(
        opre, Wot, nullptr, nullptr, nullptr, out, 0);
}

// Round 7
// 403.705 us; speedup vs baseline: 1.2495x; 1.2495x over previous
//
#include <hip/hip_runtime.h>
#include <math.h>

#define BB 2
#define SS 2048
#define DD 2048
#define QH 16
#define NKV 4
#define HD 128
#define REP 4           // QH / NKV
#define NEG_INF_F (-1e9f)

typedef __bf16 bfrag __attribute__((ext_vector_type(8)));   // 4 VGPRs
typedef float  ffrag __attribute__((ext_vector_type(4)));   // 4 VGPRs

__device__ inline unsigned short f2bf(float f) {
    unsigned u = __builtin_bit_cast(unsigned, f);
    u += 0x7fff + ((u >> 16) & 1);          // round-to-nearest-even
    return (unsigned short)(u >> 16);
}
__device__ inline float bf2f(unsigned short u) {
    unsigned v = (unsigned)u << 16;
    return __builtin_bit_cast(float, v);
}
__device__ inline bfrag ld_frag(const unsigned short* p) {
    uint4 u = *(const uint4*)p;
    return __builtin_bit_cast(bfrag, u);
}
__device__ inline void async16(const void* g, void* l) {
    __builtin_amdgcn_global_load_lds(
        (const __attribute__((address_space(1))) unsigned int*)g,
        (__attribute__((address_space(3))) unsigned int*)l, 16, 0, 0);
}

// ---------------------------------------------------------------------------
// Kernel A: elementwise cast x fp32 -> bf16 (8 elems/thread).
// ---------------------------------------------------------------------------
__global__ void cast_x_kernel(const float* __restrict__ x,
                              unsigned short* __restrict__ xb, int n)
{
    const int i = (blockIdx.x * blockDim.x + threadIdx.x) * 8;
    if (i >= n) return;
    float4 a = *(const float4*)(x + i);
    float4 b = *(const float4*)(x + i + 4);
    unsigned short o[8];
    o[0] = f2bf(a.x); o[1] = f2bf(a.y); o[2] = f2bf(a.z); o[3] = f2bf(a.w);
    o[4] = f2bf(b.x); o[5] = f2bf(b.y); o[6] = f2bf(b.z); o[7] = f2bf(b.w);
    *(uint4*)(xb + i) = *(uint4*)o;
}

// ---------------------------------------------------------------------------
// Kernel B: tiled transpose-cast. in: [batch][R][C] fp32 -> out: [batch][C][R]
// bf16. 32x32 tiles via padded LDS; both sides coalesced.
// ---------------------------------------------------------------------------
__global__ __launch_bounds__(256) void tcast_kernel(
    const float* __restrict__ in, unsigned short* __restrict__ out,
    int R, int C)
{
    __shared__ float tile[32][33];
    const size_t bofs = (size_t)blockIdx.z * R * C;
    in  += bofs;
    out += bofs;
    const int c0 = blockIdx.x * 32, r0 = blockIdx.y * 32;
    const int tx = threadIdx.x & 31, ty = threadIdx.x >> 5;   // ty: 0..7
    #pragma unroll
    for (int k = 0; k < 4; ++k)
        tile[ty + 8 * k][tx] = in[(size_t)(r0 + ty + 8 * k) * C + c0 + tx];
    __syncthreads();
    #pragma unroll
    for (int k = 0; k < 4; ++k)
        out[(size_t)(c0 + ty + 8 * k) * R + r0 + tx] =
            f2bf(tile[tx][ty + 8 * k]);
}

// ---------------------------------------------------------------------------
// Kernel C: bf16 MFMA GEMM, m97 structure. 128x128 tile, BK=32, 4 waves x
// 4x4 16x16x32 MFMA, global_load_lds width-16 staging.
// mode 0: fp32 out [row][2048] (oproj).
// mode 1: qkv — q,k natural bf16; v stored TRANSPOSED to vt[b][n][h][s].
// ---------------------------------------------------------------------------
__global__ __launch_bounds__(256) void gemm_bt_kernel(
    const unsigned short* __restrict__ A,
    const unsigned short* __restrict__ Bt,
    unsigned short* __restrict__ q_out, unsigned short* __restrict__ k_out,
    unsigned short* __restrict__ vt_out, float* __restrict__ f_out,
    int mode)
{
    const int m0 = blockIdx.x * 128;
    const int n0 = blockIdx.y * 128;
    const int tid  = threadIdx.x;
    const int w    = tid >> 6, lane = tid & 63;
    const int l16  = lane & 15, quad = lane >> 4;
    const int wm = (w >> 1) * 64, wn = (w & 1) * 64;

    __shared__ unsigned short As[128 * 32];   // [m][k], 64 B rows
    __shared__ unsigned short Bs[128 * 32];   // [n][k]

    ffrag acc[4][4];
    #pragma unroll
    for (int mi = 0; mi < 4; ++mi)
        #pragma unroll
        for (int ni = 0; ni < 4; ++ni)
            acc[mi][ni] = (ffrag){0.f, 0.f, 0.f, 0.f};

    for (int k0 = 0; k0 < 2048; k0 += 32) {
        __syncthreads();
        #pragma unroll
        for (int j = 0; j < 2; ++j) {
            const int i   = (j * 4 + w) * 64 + lane;   // chunk 0..511
            const int row = i >> 2, seg = i & 3;
            async16(&A [(size_t)(m0 + row) * 2048 + k0 + seg * 8],
                    (char*)As + i * 16);
            async16(&Bt[(size_t)(n0 + row) * 2048 + k0 + seg * 8],
                    (char*)Bs + i * 16);
        }
        __syncthreads();

        bfrag af[4], bfr[4];
        #pragma unroll
        for (int mi = 0; mi < 4; ++mi)
            af[mi] = ld_frag(&As[(wm + mi * 16 + l16) * 32 + quad * 8]);
        #pragma unroll
        for (int ni = 0; ni < 4; ++ni)
            bfr[ni] = ld_frag(&Bs[(wn + ni * 16 + l16) * 32 + quad * 8]);
        #pragma unroll
        for (int mi = 0; mi < 4; ++mi)
            #pragma unroll
            for (int ni = 0; ni < 4; ++ni)
                acc[mi][ni] = __builtin_amdgcn_mfma_f32_16x16x32_bf16(
                    af[mi], bfr[ni], acc[mi][ni], 0, 0, 0);
    }

    if (mode == 0) {
        #pragma unroll
        for (int mi = 0; mi < 4; ++mi)
            #pragma unroll
            for (int ni = 0; ni < 4; ++ni) {
                const int col = n0 + wn + ni * 16 + l16;
                #pragma unroll
                for (int r = 0; r < 4; ++r) {
                    const int row = m0 + wm + mi * 16 + quad * 4 + r;
                    f_out[(size_t)row * 2048 + col] = acc[mi][ni][r];
                }
            }
    } else if (n0 < 2560) {
        unsigned short* dst;
        int colbase, stride;
        if (n0 < 2048)      { dst = q_out; colbase = n0;        stride = 2048; }
        else                { dst = k_out; colbase = n0 - 2048; stride = 512;  }
        #pragma unroll
        for (int mi = 0; mi < 4; ++mi)
            #pragma unroll
            for (int ni = 0; ni < 4; ++ni) {
                const int col = colbase + wn + ni * 16 + l16;
                #pragma unroll
                for (int r = 0; r < 4; ++r) {
                    const int row = m0 + wm + mi * 16 + quad * 4 + r;
                    dst[(size_t)row * stride + col] = f2bf(acc[mi][ni][r]);
                }
            }
    } else {
        // v region: transposed store vt[b][n][h][s], 4 bf16 (s..s+3) packed
        const int c3 = n0 - 2560;
        #pragma unroll
        for (int mi = 0; mi < 4; ++mi)
            #pragma unroll
            for (int ni = 0; ni < 4; ++ni) {
                const int col = c3 + wn + ni * 16 + l16;   // 0..511
                const int nh = col >> 7, h = col & 127;
                const int row0 = m0 + wm + mi * 16 + quad * 4;
                const int b = row0 >> 11, s = row0 & 2047;
                unsigned short pk[4];
                #pragma unroll
                for (int r = 0; r < 4; ++r) pk[r] = f2bf(acc[mi][ni][r]);
                *(uint2*)&vt_out[(((size_t)b * NKV + nh) * HD + h) * SS + s] =
                    *(uint2*)pk;
            }
    }
}

// ---------------------------------------------------------------------------
// Kernel D: RoPE in-place on bf16 q and k.
// ---------------------------------------------------------------------------
__global__ void rope_kernel(unsigned short* __restrict__ q,
                            unsigned short* __restrict__ k,
                            const int* __restrict__ positions)
{
    const int qpairs = BB * SS * QH * 64;
    const int kpairs = BB * SS * NKV * 64;
    int idx = blockIdx.x * blockDim.x + threadIdx.x;
    unsigned short* base;
    int nh;
    if (idx < qpairs) { base = q; nh = QH; }
    else {
        idx -= qpairs;
        if (idx >= kpairs) return;
        base = k; nh = NKV;
    }
    const int hh   = idx & 63;
    const int rest = idx >> 6;
    const int head = rest % nh;
    const int bs   = rest / nh;
    const int s    = bs % SS;

    unsigned short* p = base + ((size_t)bs * nh + head) * HD;
    const float pos = (float)positions[s];
    const float inv_ts = powf(10000.0f, -(float)hh * (1.0f / 64.0f));
    const float angle = pos * inv_ts;
    const float sn = sinf(angle), cs = cosf(angle);
    const float x1 = bf2f(p[hh]), x2 = bf2f(p[hh + 64]);
    p[hh]      = f2bf(x1 * cs - x2 * sn);
    p[hh + 64] = f2bf(x2 * cs + x1 * sn);
}

// ---------------------------------------------------------------------------
// Kernel E: causal flash attention v5.
//  - Sequential tile pairing: block bx does tile (31-bx) then tile bx —
//    exactly 33 rounds/block, 512 blocks = 2 resident/CU, zero tail,
//    single-tile register footprint (no spills).
//  - Double-buffered K/V staging: async16 for round t+1 issued before
//    compute of round t; one barrier per round; load latency overlaps MFMA.
//  - K LDS [buf][hchunk][t][32], V^T LDS [buf][tchunk][h][32], async16
//    lane-sequential writes = conflict-free. P per-wave [kchunk][16][34].
// ---------------------------------------------------------------------------
__global__ __launch_bounds__(256, 2) void attn_kernel(
    const unsigned short* __restrict__ qb,
    const unsigned short* __restrict__ kb,
    const unsigned short* __restrict__ vt,
    unsigned short* __restrict__ o)
{
    const int bh = blockIdx.y;
    const int b  = bh / QH, qh = bh % QH;
    const int n  = qh / REP;

    const int tid  = threadIdx.x;
    const int w    = tid >> 6;
    const int lane = tid & 63;
    const int l16  = lane & 15;
    const int quad = lane >> 4;

    __shared__ unsigned short Ks[2][4][64][32];    // 32 KB
    __shared__ unsigned short Vs[2][2][128][32];   // 32 KB
    __shared__ unsigned short Ps[4][2][16][34];    // 8.5 KB

    const unsigned short* kbase = kb + (size_t)b * (SS * NKV * HD) + n * HD;
    const unsigned short* vbase = vt + ((size_t)b * NKV + n) * HD * SS;
    const float scale = 0.08838834764831845f;   // 1/sqrt(128)

    for (int ph = 0; ph < 2; ++ph) {
        const int tile = ph == 0 ? (31 - (int)blockIdx.x) : (int)blockIdx.x;
        const int s0 = tile * 64;
        const int rbase = s0 + w * 16 + quad * 4;

        bfrag qf[4];
        {
            const unsigned short* qp =
                qb + ((size_t)(b * SS + s0 + w * 16 + l16) * QH + qh) * HD
                   + quad * 8;
            #pragma unroll
            for (int c = 0; c < 4; ++c) qf[c] = ld_frag(qp + c * 32);
        }
        ffrag oacc[8];
        #pragma unroll
        for (int t = 0; t < 8; ++t) oacc[t] = (ffrag){0.f, 0.f, 0.f, 0.f};
        float mr[4], lr[4];
        #pragma unroll
        for (int r = 0; r < 4; ++r) { mr[r] = -1e30f; lr[r] = 0.0f; }

        // prologue: stage first K/V tile into buffer 0
        #pragma unroll
        for (int j = 0; j < 4; ++j) {
            const int s = j * 256 + tid;
            {   const int c = s >> 8, t = (s >> 2) & 63, seg = s & 3;
                async16(kbase + (size_t)t * (NKV * HD) + c * 32 + seg * 8,
                        (char*)&Ks[0][0][0][0] + s * 16);
            }
            {   const int c = s >> 9, h = (s >> 2) & 127, seg = s & 3;
                async16(vbase + (size_t)h * SS + c * 32 + seg * 8,
                        (char*)&Vs[0][0][0][0] + s * 16);
            }
        }
        __syncthreads();

        int p = 0;
        for (int t0 = 0; t0 <= s0; t0 += 64, p ^= 1) {
            // stage next tile into the other buffer (overlaps compute below)
            if (t0 + 64 <= s0) {
                const int tn = t0 + 64;
                #pragma unroll
                for (int j = 0; j < 4; ++j) {
                    const int s = j * 256 + tid;
                    {   const int c = s >> 8, t = (s >> 2) & 63, seg = s & 3;
                        async16(kbase + (size_t)(tn + t) * (NKV * HD)
                                      + c * 32 + seg * 8,
                                (char*)&Ks[p ^ 1][0][0][0] + s * 16);
                    }
                    {   const int c = s >> 9, h = (s >> 2) & 127, seg = s & 3;
                        async16(vbase + (size_t)h * SS + tn + c * 32 + seg * 8,
                                (char*)&Vs[p ^ 1][0][0][0] + s * 16);
                    }
                }
            }

            // --- QK^T on buffer p
            ffrag sc[4];
            #pragma unroll
            for (int t = 0; t < 4; ++t) sc[t] = (ffrag){0.f, 0.f, 0.f, 0.f};
            #pragma unroll
            for (int c = 0; c < 4; ++c) {
                #pragma unroll
                for (int t = 0; t < 4; ++t) {
                    bfrag kfr = ld_frag(&Ks[p][c][t * 16 + l16][quad * 8]);
                    sc[t] = __builtin_amdgcn_mfma_f32_16x16x32_bf16(
                        qf[c], kfr, sc[t], 0, 0, 0);
                }
            }

            // --- mask + online softmax (C layout: row=quad*4+r, col=l16)
            const bool diag = (t0 == s0);
            float sv[4][4];
            #pragma unroll
            for (int t = 0; t < 4; ++t) {
                const int col = t0 + t * 16 + l16;
                #pragma unroll
                for (int r = 0; r < 4; ++r) {
                    float s = sc[t][r] * scale;
                    if (diag && (col > rbase + r)) s = NEG_INF_F;
                    sv[t][r] = s;
                }
            }
            #pragma unroll
            for (int r = 0; r < 4; ++r) {
                float tm = fmaxf(fmaxf(sv[0][r], sv[1][r]),
                                 fmaxf(sv[2][r], sv[3][r]));
                #pragma unroll
                for (int off = 1; off < 16; off <<= 1)
                    tm = fmaxf(tm, __shfl_xor(tm, off));
                const float mnew  = fmaxf(mr[r], tm);
                const float alpha = __expf(mr[r] - mnew);
                float p0 = __expf(sv[0][r] - mnew);
                float p1 = __expf(sv[1][r] - mnew);
                float p2 = __expf(sv[2][r] - mnew);
                float p3 = __expf(sv[3][r] - mnew);
                float ps = p0 + p1 + p2 + p3;
                #pragma unroll
                for (int off = 1; off < 16; off <<= 1)
                    ps += __shfl_xor(ps, off);
                lr[r] = lr[r] * alpha + ps;
                mr[r] = mnew;
                #pragma unroll
                for (int t = 0; t < 8; ++t) oacc[t][r] *= alpha;
                const int row = quad * 4 + r;
                Ps[w][0][row][0 * 16 + l16] = f2bf(p0);
                Ps[w][0][row][1 * 16 + l16] = f2bf(p1);
                Ps[w][1][row][0 * 16 + l16] = f2bf(p2);
                Ps[w][1][row][1 * 16 + l16] = f2bf(p3);
            }
            // wave-private Ps: same-wave LDS ordering, no barrier needed

            // --- PV on buffer p
            #pragma unroll
            for (int c = 0; c < 2; ++c) {
                bfrag pf = ld_frag(&Ps[w][c][l16][quad * 8]);
                #pragma unroll
                for (int t = 0; t < 8; ++t) {
                    bfrag vf = ld_frag(&Vs[p][c][t * 16 + l16][quad * 8]);
                    oacc[t] = __builtin_amdgcn_mfma_f32_16x16x32_bf16(
                        pf, vf, oacc[t], 0, 0, 0);
                }
            }

            // one barrier per round: drains next-tile staging (vmcnt0) after
            // compute, and orders this round's LDS reads vs next overwrite
            __syncthreads();
        }

        // --- epilogue for this tile
        #pragma unroll
        for (int r = 0; r < 4; ++r) {
            const float invl = 1.0f / lr[r];
            const int row = rbase + r;
            unsigned short* op = o + ((size_t)(b * SS + row) * QH + qh) * HD;
            #pragma unroll
            for (int t = 0; t < 8; ++t)
                op[t * 16 + l16] = f2bf(oacc[t][r] * invl);
        }
    }
}

// ---------------------------------------------------------------------------
extern "C" void kernel_launch(void* const* d_in, const int* in_sizes, int n_in,
                              void* d_out, int out_size, void* d_ws,
                              size_t ws_size, hipStream_t stream)
{
    const float* x         = (const float*)d_in[0];
    const int*   positions = (const int*)d_in[1];
    const float* Wq        = (const float*)d_in[2];
    const float* Wk        = (const float*)d_in[3];
    const float* Wv        = (const float*)d_in[4];
    const float* Wo        = (const float*)d_in[5];
    float* out = (float*)d_out;

    // workspace (60 MB):
    //   [ 0,16)  xb  bf16 [4096][2048]      -- aliased by opre after qkv gemm
    //   [16,28)  Wqkvt bf16 [3072][2048]    (B^T)
    //   [28,36)  Wot bf16 [2048][2048]      (B^T)
    //   [36,52)  qbf bf16 [4096][16][128]
    //   [52,56)  kbf bf16 [4096][4][128]
    //   [56,60)  vtb bf16 [2][4][128][2048] (V^T: [b][n][h][s])
    char* ws = (char*)d_ws;
    unsigned short* xb    = (unsigned short*)ws;
    unsigned short* Wqkvt = (unsigned short*)(ws + (16u << 20));
    unsigned short* Wot   = (unsigned short*)(ws + (28u << 20));
    unsigned short* qbf   = (unsigned short*)(ws + (36u << 20));
    unsigned short* kbf   = (unsigned short*)(ws + (52u << 20));
    unsigned short* vtb   = (unsigned short*)(ws + (56u << 20));
    unsigned short* opre  = xb;   // alias: xb dead after qkv gemm

    const int nx = BB * SS * DD;                     // 8,388,608
    cast_x_kernel<<<nx / (8 * 256), 256, 0, stream>>>(x, xb, nx);

    // weights -> B^T bf16
    tcast_kernel<<<dim3(4, 64, 16), 256, 0, stream>>>(Wq, Wqkvt, 2048, 128);
    tcast_kernel<<<dim3(4, 64, 4), 256, 0, stream>>>(
        Wk, Wqkvt + (size_t)16 * 128 * 2048, 2048, 128);
    tcast_kernel<<<dim3(4, 64, 4), 256, 0, stream>>>(
        Wv, Wqkvt + (size_t)20 * 128 * 2048, 2048, 128);
    tcast_kernel<<<dim3(64, 64, 1), 256, 0, stream>>>(Wo, Wot, 2048, 2048);

    // qkv projection (v stored transposed)
    gemm_bt_kernel<<<dim3(32, 24), 256, 0, stream>>>(
        xb, Wqkvt, qbf, kbf, vtb, nullptr, 1);

    const int pairs = BB * SS * (QH + NKV) * 64;
    rope_kernel<<<(pairs + 255) / 256, 256, 0, stream>>>(qbf, kbf, positions);

    // attention: 512 blocks, paired tiles (33 rounds each), 2 blocks/CU
    dim3 g2(16, BB * QH);
    attn_kernel<<<g2, 256, 0, stream>>>(qbf, kbf, vtb, opre);

    // output projection
    gemm_bt_kernel<<<dim3(32, 16), 256, 0, stream>>>(
        opre, Wot, nullptr, nullptr, nullptr, out, 0);
}